// Round 7
// baseline (292.792 us; speedup 1.0000x reference)
//
#include <hip/hip_runtime.h>
#include <math.h>

#define NB 16
#define NH 128
#define NP 64
#define NL 8192
#define NCHUNK 64   // NL / 128

__device__ __forceinline__ unsigned toBF(unsigned u) {
  // round-to-nearest-even f32 -> bf16 (top 16 bits); inputs are finite here
  return (u + 0x7FFFu + ((u >> 16) & 1u)) >> 16;
}

// ---- K1: Bu = B@u fused with chunk-local scan over the 128-l tile ------------
// grid (64, 16), block 256. Writes x_local packed bf16 (re lo16, im hi16) and
// per-chunk totals Echunk[b][c][p] (fp32).
__global__ __launch_bounds__(256) void k_bu_scan(
    const float* __restrict__ u, const float* __restrict__ Bre,
    const float* __restrict__ Bim, const float* __restrict__ Lre,
    const float* __restrict__ Lim, unsigned* __restrict__ xbf,
    float2* __restrict__ Echunk) {
  __shared__ __align__(16) float sBre[32][68];   // [h][p], padded; reused as E later
  __shared__ float sBim[32][68];
  __shared__ float sU[32][128];
  const int b  = blockIdx.y;
  const int c  = blockIdx.x;        // l-chunk
  const int l0 = c * 128;
  const int t  = threadIdx.x;
  const int tp = t & 15;            // p = tp*4 + i
  const int tl = t >> 4;            // l = l0 + tl*8 + j
  float accRe[4][8], accIm[4][8];
  #pragma unroll
  for (int i = 0; i < 4; ++i)
    #pragma unroll
    for (int j = 0; j < 8; ++j) { accRe[i][j] = 0.f; accIm[i][j] = 0.f; }

  for (int ht = 0; ht < 4; ++ht) {
    const int h0 = ht * 32;
    #pragma unroll
    for (int idx = t; idx < 2048; idx += 256) {
      int h = idx & 31, p = idx >> 5;
      sBre[h][p] = Bre[p * NH + h0 + h];
      sBim[h][p] = Bim[p * NH + h0 + h];
    }
    #pragma unroll
    for (int idx = t; idx < 32 * 128; idx += 256) {
      int l = idx & 127, h = idx >> 7;
      sU[h][l] = u[((size_t)(b * NH + h0 + h)) * NL + l0 + l];
    }
    __syncthreads();
    #pragma unroll 4
    for (int h = 0; h < 32; ++h) {
      float4 br4 = *(const float4*)&sBre[h][tp * 4];
      float4 bi4 = *(const float4*)&sBim[h][tp * 4];
      float4 ua  = *(const float4*)&sU[h][tl * 8];
      float4 ub  = *(const float4*)&sU[h][tl * 8 + 4];
      float uu[8] = {ua.x, ua.y, ua.z, ua.w, ub.x, ub.y, ub.z, ub.w};
      float brr[4] = {br4.x, br4.y, br4.z, br4.w};
      float bii[4] = {bi4.x, bi4.y, bi4.z, bi4.w};
      #pragma unroll
      for (int i = 0; i < 4; ++i)
        #pragma unroll
        for (int j = 0; j < 8; ++j) {
          accRe[i][j] = fmaf(brr[i], uu[j], accRe[i][j]);
          accIm[i][j] = fmaf(bii[i], uu[j], accIm[i][j]);
        }
    }
    __syncthreads();   // also guarantees sBre free for reuse after the loop
  }

  // ---- local scan over this thread's 8 contiguous l (zero initial state) ----
  float lr[4], li[4];
  #pragma unroll
  for (int i = 0; i < 4; ++i) { lr[i] = Lre[tp * 4 + i]; li[i] = Lim[tp * 4 + i]; }
  #pragma unroll
  for (int i = 0; i < 4; ++i) {
    float xr = 0.f, xi = 0.f;
    #pragma unroll
    for (int j = 0; j < 8; ++j) {
      float nr = fmaf(lr[i], xr, fmaf(-li[i], xi, accRe[i][j]));
      float ni = fmaf(lr[i], xi, fmaf( li[i], xr, accIm[i][j]));
      xr = nr; xi = ni; accRe[i][j] = xr; accIm[i][j] = xi;
    }
  }

  // ---- Hillis scan over the 16 sub-chunks (factor Lam^8), in LDS ------------
  float2* E = reinterpret_cast<float2*>(&sBre[0][0]);  // 64*17 float2 = 8704 B
  #define EL(p, q) E[(p) * 17 + (q)]
  #pragma unroll
  for (int i = 0; i < 4; ++i)
    EL(tp * 4 + i, tl) = make_float2(accRe[i][7], accIm[i][7]);

  float wr[4], wi[4];  // Lam^8 per i, then squared each Hillis step
  #pragma unroll
  for (int i = 0; i < 4; ++i) {
    float ar = lr[i], ai = li[i];
    #pragma unroll
    for (int k = 0; k < 3; ++k) { float nr = ar * ar - ai * ai; ai = 2.f * ar * ai; ar = nr; }
    wr[i] = ar; wi[i] = ai;
  }
  __syncthreads();
  #pragma unroll
  for (int d = 1; d < 16; d <<= 1) {
    float2 rv[4];
    #pragma unroll
    for (int i = 0; i < 4; ++i)
      rv[i] = (tl >= d) ? EL(tp * 4 + i, tl - d) : make_float2(0.f, 0.f);
    __syncthreads();
    if (tl >= d) {
      #pragma unroll
      for (int i = 0; i < 4; ++i) {
        float2 cur = EL(tp * 4 + i, tl);
        cur.x += wr[i] * rv[i].x - wi[i] * rv[i].y;
        cur.y += wr[i] * rv[i].y + wi[i] * rv[i].x;
        EL(tp * 4 + i, tl) = cur;
      }
    }
    __syncthreads();
    #pragma unroll
    for (int i = 0; i < 4; ++i) {
      float nr = wr[i] * wr[i] - wi[i] * wi[i];
      wi[i] = 2.f * wr[i] * wi[i]; wr[i] = nr;
    }
  }

  // incoming state for this thread's sub-chunk, chunk total to global
  float2 cin[4];
  #pragma unroll
  for (int i = 0; i < 4; ++i)
    cin[i] = (tl > 0) ? EL(tp * 4 + i, tl - 1) : make_float2(0.f, 0.f);
  if (t < 64) {
    float2 tot = EL(t, 15);
    Echunk[((size_t)(b * NCHUNK + c)) * NP + t] = tot;
  }

  // apply sub-chunk carry: x_j += Lam^{j+1} * cin
  #pragma unroll
  for (int i = 0; i < 4; ++i) {
    float cr = cin[i].x, ci = cin[i].y;
    #pragma unroll
    for (int j = 0; j < 8; ++j) {
      float nr = lr[i] * cr - li[i] * ci;
      float nc = lr[i] * ci + li[i] * cr;
      cr = nr; ci = nc;
      accRe[i][j] += cr; accIm[i][j] += ci;
    }
  }

  // store x_local as packed bf16 (re lo16, im hi16)
  #pragma unroll
  for (int i = 0; i < 4; ++i) {
    size_t base = ((size_t)(b * NP + tp * 4 + i)) * NL + l0 + tl * 8;
    uint4 w0, w1;
    w0.x = toBF(__float_as_uint(accRe[i][0])) | (toBF(__float_as_uint(accIm[i][0])) << 16);
    w0.y = toBF(__float_as_uint(accRe[i][1])) | (toBF(__float_as_uint(accIm[i][1])) << 16);
    w0.z = toBF(__float_as_uint(accRe[i][2])) | (toBF(__float_as_uint(accIm[i][2])) << 16);
    w0.w = toBF(__float_as_uint(accRe[i][3])) | (toBF(__float_as_uint(accIm[i][3])) << 16);
    w1.x = toBF(__float_as_uint(accRe[i][4])) | (toBF(__float_as_uint(accIm[i][4])) << 16);
    w1.y = toBF(__float_as_uint(accRe[i][5])) | (toBF(__float_as_uint(accIm[i][5])) << 16);
    w1.z = toBF(__float_as_uint(accRe[i][6])) | (toBF(__float_as_uint(accIm[i][6])) << 16);
    w1.w = toBF(__float_as_uint(accRe[i][7])) | (toBF(__float_as_uint(accIm[i][7])) << 16);
    *(uint4*)&xbf[base]     = w0;
    *(uint4*)&xbf[base + 4] = w1;
  }
  #undef EL
}

// ---- K2: parallel carry scan. grid (NP, NB), 64 threads (= one wave, t = c). -
// Inclusive wave scan of chunk totals with factor Lam^128 via shfl_up;
// exclusive result -> carryg. Blocks with b==0 also fill powtab (binary exp).
__global__ __launch_bounds__(64) void k_carry(
    const float2* __restrict__ Echunk, const float* __restrict__ Lre,
    const float* __restrict__ Lim, float2* __restrict__ carryg,
    float2* __restrict__ powtab) {
  const int p = blockIdx.x;
  const int b = blockIdx.y;
  const int t = threadIdx.x;      // chunk index c
  const float lr = Lre[p], li = Lim[p];
  // W = Lam^128 via 7 squarings
  float wr = lr, wi = li;
  #pragma unroll
  for (int k = 0; k < 7; ++k) { float nr = wr * wr - wi * wi; wi = 2.f * wr * wi; wr = nr; }
  float2 e = Echunk[((size_t)(b * NCHUNK + t)) * NP + p];
  float sr = e.x, si = e.y;
  float fr = wr, fi = wi;         // W^(2^k) per scan step
  #pragma unroll
  for (int d = 1; d < 64; d <<= 1) {
    float pr = __shfl_up(sr, d);
    float pi = __shfl_up(si, d);
    if (t >= d) { sr += fr * pr - fi * pi; si += fr * pi + fi * pr; }
    float nr = fr * fr - fi * fi; fi = 2.f * fr * fi; fr = nr;
  }
  float cr = __shfl_up(sr, 1);
  float ci = __shfl_up(si, 1);
  if (t == 0) { cr = 0.f; ci = 0.f; }
  carryg[((size_t)(b * NCHUNK + t)) * NP + p] = make_float2(cr, ci);

  if (b == 0) {
    // powtab[p*128 + j] = Lam^{j+1}; this lane does j = t and j = t+64
    float ar = lr, ai = li, br = 1.f, bi = 0.f;
    int e1 = t + 1;
    while (e1) {
      if (e1 & 1) { float nr = br * ar - bi * ai; bi = br * ai + bi * ar; br = nr; }
      float nr = ar * ar - ai * ai; ai = 2.f * ar * ai; ar = nr;
      e1 >>= 1;
    }
    powtab[p * 128 + t] = make_float2(br, bi);
    float qr = lr, qi = li;       // Lam^64 via 6 squarings
    #pragma unroll
    for (int k = 0; k < 6; ++k) { float nr = qr * qr - qi * qi; qi = 2.f * qr * qi; qr = nr; }
    float hr = br * qr - bi * qi, hi = br * qi + bi * qr;
    powtab[p * 128 + t + 64] = make_float2(hr, hi);
  }
}

// ---- K3: out = gelu( Re(C @ (xbf + Lam^{j+1}*carry)) + diag(D)*u ) -----------
// grid (64, 16), block 256; x-tile loads software-pipelined through registers.
__global__ __launch_bounds__(256) void k_out(
    const unsigned* __restrict__ xs, const float* __restrict__ u,
    const float* __restrict__ Cre, const float* __restrict__ Cim,
    const float* __restrict__ D, const float2* __restrict__ carryg,
    const float2* __restrict__ powtab, float* __restrict__ out) {
  __shared__ float sCre[16][132];
  __shared__ float sCim[16][132];
  __shared__ float sXre[16][128];
  __shared__ float sXim[16][128];
  __shared__ float sDd[128];
  const int b  = blockIdx.y;
  const int c  = blockIdx.x;
  const int l0 = c * 128;
  const int t  = threadIdx.x;
  const int lane = t & 63, w = t >> 6;
  const int th = (lane & 7) + 8 * (w & 1);
  const int tl = (lane >> 3) + 8 * (w >> 1);
  const int lfix = t & 127;        // fixed l for this thread in load loops
  const int ppb  = t >> 7;         // pp parity base

  if (t < 128) sDd[t] = D[t * NH + t];

  float acc[8][8];
  #pragma unroll
  for (int i = 0; i < 8; ++i)
    #pragma unroll
    for (int j = 0; j < 8; ++j) acc[i][j] = 0.f;

  unsigned xg[8]; float2 gp[8], gc[8];
  // prologue: issue loads for pt = 0
  #pragma unroll
  for (int k = 0; k < 8; ++k) {
    int pp = ppb + 2 * k;
    xg[k] = xs[((size_t)(b * NP + pp)) * NL + l0 + lfix];
    gp[k] = powtab[pp * 128 + lfix];
    gc[k] = carryg[((size_t)(b * NCHUNK + c)) * NP + pp];
  }

  #pragma unroll
  for (int pt = 0; pt < 4; ++pt) {
    const int p0 = pt * 16;
    __syncthreads();   // previous compute done; LDS writable (covers sDd on pt=0)
    // C tile -> LDS
    #pragma unroll
    for (int idx = t; idx < 2048; idx += 256) {
      int pp = idx & 15, h = idx >> 4;
      sCre[pp][h] = Cre[h * NP + p0 + pp];
      sCim[pp][h] = Cim[h * NP + p0 + pp];
    }
    // x tile (regs loaded last iteration): unpack bf16 + carry apply -> LDS
    #pragma unroll
    for (int k = 0; k < 8; ++k) {
      int pp = ppb + 2 * k;
      float xlr = __uint_as_float(xg[k] << 16);
      float xli = __uint_as_float(xg[k] & 0xFFFF0000u);
      float xr = xlr + gp[k].x * gc[k].x - gp[k].y * gc[k].y;
      float xi = xli + gp[k].x * gc[k].y + gp[k].y * gc[k].x;
      sXre[pp][lfix] = xr; sXim[pp][lfix] = xi;
    }
    __syncthreads();
    // issue next pt's loads; they complete under the FMA loop below
    if (pt < 3) {
      const int p1 = (pt + 1) * 16;
      #pragma unroll
      for (int k = 0; k < 8; ++k) {
        int pp = ppb + 2 * k;
        xg[k] = xs[((size_t)(b * NP + p1 + pp)) * NL + l0 + lfix];
        gp[k] = powtab[(p1 + pp) * 128 + lfix];
        gc[k] = carryg[((size_t)(b * NCHUNK + c)) * NP + p1 + pp];
      }
    }
    #pragma unroll 4
    for (int pp = 0; pp < 16; ++pp) {
      float4 ca = *(const float4*)&sCre[pp][th * 8];
      float4 cb = *(const float4*)&sCre[pp][th * 8 + 4];
      float4 ia = *(const float4*)&sCim[pp][th * 8];
      float4 ib = *(const float4*)&sCim[pp][th * 8 + 4];
      float4 xa = *(const float4*)&sXre[pp][tl * 8];
      float4 xb = *(const float4*)&sXre[pp][tl * 8 + 4];
      float4 ya = *(const float4*)&sXim[pp][tl * 8];
      float4 yb = *(const float4*)&sXim[pp][tl * 8 + 4];
      float cr[8] = {ca.x, ca.y, ca.z, ca.w, cb.x, cb.y, cb.z, cb.w};
      float ci[8] = {ia.x, ia.y, ia.z, ia.w, ib.x, ib.y, ib.z, ib.w};
      float xr[8] = {xa.x, xa.y, xa.z, xa.w, xb.x, xb.y, xb.z, xb.w};
      float xi[8] = {ya.x, ya.y, ya.z, ya.w, yb.x, yb.y, yb.z, yb.w};
      #pragma unroll
      for (int i = 0; i < 8; ++i)
        #pragma unroll
        for (int j = 0; j < 8; ++j) {
          acc[i][j] = fmaf(cr[i], xr[j], acc[i][j]);
          acc[i][j] = fmaf(-ci[i], xi[j], acc[i][j]);
        }
    }
  }

  #pragma unroll
  for (int i = 0; i < 8; ++i) {
    const int h = th * 8 + i;
    const float dd = sDd[h];
    size_t rb = ((size_t)(b * NH + h)) * NL + l0 + tl * 8;
    float4 u0 = *(const float4*)&u[rb];
    float4 u1 = *(const float4*)&u[rb + 4];
    float uu[8] = {u0.x, u0.y, u0.z, u0.w, u1.x, u1.y, u1.z, u1.w};
    float r[8];
    #pragma unroll
    for (int j = 0; j < 8; ++j) {
      float vv = acc[i][j] + dd * uu[j];
      r[j] = 0.5f * vv * (1.0f + erff(vv * 0.70710678118654752f));
    }
    *(float4*)&out[rb]     = make_float4(r[0], r[1], r[2], r[3]);
    *(float4*)&out[rb + 4] = make_float4(r[4], r[5], r[6], r[7]);
  }
}

extern "C" void kernel_launch(void* const* d_in, const int* in_sizes, int n_in,
                              void* d_out, int out_size, void* d_ws, size_t ws_size,
                              hipStream_t stream) {
  (void)in_sizes; (void)n_in; (void)out_size; (void)ws_size;
  const float* u   = (const float*)d_in[0];
  const float* Lre = (const float*)d_in[1];
  const float* Lim = (const float*)d_in[2];
  const float* Bre = (const float*)d_in[3];
  const float* Bim = (const float*)d_in[4];
  const float* Cre = (const float*)d_in[5];
  const float* Cim = (const float*)d_in[6];
  const float* Dm  = (const float*)d_in[7];
  float* out = (float*)d_out;

  char* wsb = (char*)d_ws;
  unsigned* xbf  = (unsigned*)wsb;                            // 32 MiB packed bf16
  float2* Echunk = (float2*)(wsb + 33554432);                 // 512 KiB
  float2* carryg = (float2*)(wsb + 33554432 + 524288);        // 512 KiB
  float2* powtab = (float2*)(wsb + 33554432 + 1048576);       // 64 KiB

  dim3 g(NL / 128, NB);
  k_bu_scan<<<g, 256, 0, stream>>>(u, Bre, Bim, Lre, Lim, xbf, Echunk);
  dim3 gc(NP, NB);
  k_carry<<<gc, 64, 0, stream>>>(Echunk, Lre, Lim, carryg, powtab);
  k_out<<<g, 256, 0, stream>>>(xbf, u, Cre, Cim, Dm, carryg, powtab, out);
}

// Round 8
// 259.461 us; speedup vs baseline: 1.1285x; 1.1285x over previous
//
#include <hip/hip_runtime.h>
#include <math.h>

#define NB 16
#define NH 128
#define NP 64
#define NL 8192
#define NCHUNK 64   // NL / 128

// ---- K1: Bu = B@u fused with chunk-local scan over the 128-l tile ------------
// grid (64, 16), block 256. Writes x_local (chunk-scanned, zero-init, fp32) and
// per-chunk totals Echunk[b][c][p].
__global__ __launch_bounds__(256) void k_bu_scan(
    const float* __restrict__ u, const float* __restrict__ Bre,
    const float* __restrict__ Bim, const float* __restrict__ Lre,
    const float* __restrict__ Lim, float2* __restrict__ xloc,
    float2* __restrict__ Echunk) {
  __shared__ __align__(16) float sBre[32][68];   // [h][p], padded; reused as E later
  __shared__ float sBim[32][68];
  __shared__ float sU[32][128];
  const int b  = blockIdx.y;
  const int c  = blockIdx.x;        // l-chunk
  const int l0 = c * 128;
  const int t  = threadIdx.x;
  const int tp = t & 15;            // p = tp*4 + i
  const int tl = t >> 4;            // l = l0 + tl*8 + j
  float accRe[4][8], accIm[4][8];
  #pragma unroll
  for (int i = 0; i < 4; ++i)
    #pragma unroll
    for (int j = 0; j < 8; ++j) { accRe[i][j] = 0.f; accIm[i][j] = 0.f; }

  for (int ht = 0; ht < 4; ++ht) {
    const int h0 = ht * 32;
    #pragma unroll
    for (int idx = t; idx < 2048; idx += 256) {
      int h = idx & 31, p = idx >> 5;
      sBre[h][p] = Bre[p * NH + h0 + h];
      sBim[h][p] = Bim[p * NH + h0 + h];
    }
    #pragma unroll
    for (int idx = t; idx < 32 * 128; idx += 256) {
      int l = idx & 127, h = idx >> 7;
      sU[h][l] = u[((size_t)(b * NH + h0 + h)) * NL + l0 + l];
    }
    __syncthreads();
    #pragma unroll 4
    for (int h = 0; h < 32; ++h) {
      float4 br4 = *(const float4*)&sBre[h][tp * 4];
      float4 bi4 = *(const float4*)&sBim[h][tp * 4];
      float4 ua  = *(const float4*)&sU[h][tl * 8];
      float4 ub  = *(const float4*)&sU[h][tl * 8 + 4];
      float uu[8] = {ua.x, ua.y, ua.z, ua.w, ub.x, ub.y, ub.z, ub.w};
      float brr[4] = {br4.x, br4.y, br4.z, br4.w};
      float bii[4] = {bi4.x, bi4.y, bi4.z, bi4.w};
      #pragma unroll
      for (int i = 0; i < 4; ++i)
        #pragma unroll
        for (int j = 0; j < 8; ++j) {
          accRe[i][j] = fmaf(brr[i], uu[j], accRe[i][j]);
          accIm[i][j] = fmaf(bii[i], uu[j], accIm[i][j]);
        }
    }
    __syncthreads();   // also guarantees sBre free for reuse after the loop
  }

  // ---- local scan over this thread's 8 contiguous l (zero initial state) ----
  float lr[4], li[4];
  #pragma unroll
  for (int i = 0; i < 4; ++i) { lr[i] = Lre[tp * 4 + i]; li[i] = Lim[tp * 4 + i]; }
  #pragma unroll
  for (int i = 0; i < 4; ++i) {
    float xr = 0.f, xi = 0.f;
    #pragma unroll
    for (int j = 0; j < 8; ++j) {
      float nr = fmaf(lr[i], xr, fmaf(-li[i], xi, accRe[i][j]));
      float ni = fmaf(lr[i], xi, fmaf( li[i], xr, accIm[i][j]));
      xr = nr; xi = ni; accRe[i][j] = xr; accIm[i][j] = xi;
    }
  }

  // ---- Hillis scan over the 16 sub-chunks (factor Lam^8), in LDS ------------
  float2* E = reinterpret_cast<float2*>(&sBre[0][0]);  // 64*17 float2 = 8704 B
  #define EL(p, q) E[(p) * 17 + (q)]
  #pragma unroll
  for (int i = 0; i < 4; ++i)
    EL(tp * 4 + i, tl) = make_float2(accRe[i][7], accIm[i][7]);

  float wr[4], wi[4];  // Lam^8 per i, then squared each Hillis step
  #pragma unroll
  for (int i = 0; i < 4; ++i) {
    float ar = lr[i], ai = li[i];
    #pragma unroll
    for (int k = 0; k < 3; ++k) { float nr = ar * ar - ai * ai; ai = 2.f * ar * ai; ar = nr; }
    wr[i] = ar; wi[i] = ai;
  }
  __syncthreads();
  #pragma unroll
  for (int d = 1; d < 16; d <<= 1) {
    float2 rv[4];
    #pragma unroll
    for (int i = 0; i < 4; ++i)
      rv[i] = (tl >= d) ? EL(tp * 4 + i, tl - d) : make_float2(0.f, 0.f);
    __syncthreads();
    if (tl >= d) {
      #pragma unroll
      for (int i = 0; i < 4; ++i) {
        float2 cur = EL(tp * 4 + i, tl);
        cur.x += wr[i] * rv[i].x - wi[i] * rv[i].y;
        cur.y += wr[i] * rv[i].y + wi[i] * rv[i].x;
        EL(tp * 4 + i, tl) = cur;
      }
    }
    __syncthreads();
    #pragma unroll
    for (int i = 0; i < 4; ++i) {
      float nr = wr[i] * wr[i] - wi[i] * wi[i];
      wi[i] = 2.f * wr[i] * wi[i]; wr[i] = nr;
    }
  }

  // incoming state for this thread's sub-chunk, chunk total to global
  float2 cin[4];
  #pragma unroll
  for (int i = 0; i < 4; ++i)
    cin[i] = (tl > 0) ? EL(tp * 4 + i, tl - 1) : make_float2(0.f, 0.f);
  if (t < 64) {
    float2 tot = EL(t, 15);
    Echunk[((size_t)(b * NCHUNK + c)) * NP + t] = tot;
  }

  // apply sub-chunk carry: x_j += Lam^{j+1} * cin
  #pragma unroll
  for (int i = 0; i < 4; ++i) {
    float cr = cin[i].x, ci = cin[i].y;
    #pragma unroll
    for (int j = 0; j < 8; ++j) {
      float nr = lr[i] * cr - li[i] * ci;
      float nc = lr[i] * ci + li[i] * cr;
      cr = nr; ci = nc;
      accRe[i][j] += cr; accIm[i][j] += ci;
    }
  }

  // store x_local
  #pragma unroll
  for (int i = 0; i < 4; ++i) {
    size_t base = ((size_t)(b * NP + tp * 4 + i)) * NL + l0 + tl * 8;
    #pragma unroll
    for (int j = 0; j < 8; j += 2) {
      float4 v = make_float4(accRe[i][j], accIm[i][j], accRe[i][j + 1], accIm[i][j + 1]);
      *(float4*)&xloc[base + j] = v;
    }
  }
  #undef EL
}

// ---- K2: parallel carry scan. grid (NP, NB), 64 threads (= one wave, t = c). -
// Inclusive wave scan of chunk totals with factor Lam^128 via shfl_up;
// exclusive result -> carryg. Blocks with b==0 also fill powtab (binary exp).
__global__ __launch_bounds__(64) void k_carry(
    const float2* __restrict__ Echunk, const float* __restrict__ Lre,
    const float* __restrict__ Lim, float2* __restrict__ carryg,
    float2* __restrict__ powtab) {
  const int p = blockIdx.x;
  const int b = blockIdx.y;
  const int t = threadIdx.x;      // chunk index c
  const float lr = Lre[p], li = Lim[p];
  // W = Lam^128 via 7 squarings
  float wr = lr, wi = li;
  #pragma unroll
  for (int k = 0; k < 7; ++k) { float nr = wr * wr - wi * wi; wi = 2.f * wr * wi; wr = nr; }
  float2 e = Echunk[((size_t)(b * NCHUNK + t)) * NP + p];
  float sr = e.x, si = e.y;
  float fr = wr, fi = wi;         // W^(2^k) per scan step
  #pragma unroll
  for (int d = 1; d < 64; d <<= 1) {
    float pr = __shfl_up(sr, d);
    float pi = __shfl_up(si, d);
    if (t >= d) { sr += fr * pr - fi * pi; si += fr * pi + fi * pr; }
    float nr = fr * fr - fi * fi; fi = 2.f * fr * fi; fr = nr;
  }
  float cr = __shfl_up(sr, 1);
  float ci = __shfl_up(si, 1);
  if (t == 0) { cr = 0.f; ci = 0.f; }
  carryg[((size_t)(b * NCHUNK + t)) * NP + p] = make_float2(cr, ci);

  if (b == 0) {
    // powtab[p*128 + j] = Lam^{j+1}; this lane does j = t and j = t+64
    float ar = lr, ai = li, br = 1.f, bi = 0.f;
    int e1 = t + 1;
    while (e1) {
      if (e1 & 1) { float nr = br * ar - bi * ai; bi = br * ai + bi * ar; br = nr; }
      float nr = ar * ar - ai * ai; ai = 2.f * ar * ai; ar = nr;
      e1 >>= 1;
    }
    powtab[p * 128 + t] = make_float2(br, bi);
    float qr = lr, qi = li;       // Lam^64 via 6 squarings
    #pragma unroll
    for (int k = 0; k < 6; ++k) { float nr = qr * qr - qi * qi; qi = 2.f * qr * qi; qr = nr; }
    float hr = br * qr - bi * qi, hi = br * qi + bi * qr;
    powtab[p * 128 + t + 64] = make_float2(hr, hi);
  }
}

// ---- K3: out = gelu( Re(C @ (xloc + Lam^{j+1}*carry)) + diag(D)*u ) ----------
// grid (64, 16), block 256; x-tile loads software-pipelined through registers.
__global__ __launch_bounds__(256) void k_out(
    const float2* __restrict__ xs, const float* __restrict__ u,
    const float* __restrict__ Cre, const float* __restrict__ Cim,
    const float* __restrict__ D, const float2* __restrict__ carryg,
    const float2* __restrict__ powtab, float* __restrict__ out) {
  __shared__ float sCre[16][132];
  __shared__ float sCim[16][132];
  __shared__ float sXre[16][128];
  __shared__ float sXim[16][128];
  __shared__ float sDd[128];
  const int b  = blockIdx.y;
  const int c  = blockIdx.x;
  const int l0 = c * 128;
  const int t  = threadIdx.x;
  const int lane = t & 63, w = t >> 6;
  const int th = (lane & 7) + 8 * (w & 1);
  const int tl = (lane >> 3) + 8 * (w >> 1);
  const int lfix = t & 127;        // fixed l for this thread in load loops
  const int ppb  = t >> 7;         // pp parity base

  if (t < 128) sDd[t] = D[t * NH + t];

  float acc[8][8];
  #pragma unroll
  for (int i = 0; i < 8; ++i)
    #pragma unroll
    for (int j = 0; j < 8; ++j) acc[i][j] = 0.f;

  float2 gx[8], gp[8], gc[8];
  // prologue: issue loads for pt = 0
  #pragma unroll
  for (int k = 0; k < 8; ++k) {
    int pp = ppb + 2 * k;
    gx[k] = xs[((size_t)(b * NP + pp)) * NL + l0 + lfix];
    gp[k] = powtab[pp * 128 + lfix];
    gc[k] = carryg[((size_t)(b * NCHUNK + c)) * NP + pp];
  }

  #pragma unroll
  for (int pt = 0; pt < 4; ++pt) {
    const int p0 = pt * 16;
    __syncthreads();   // previous compute done; LDS writable (covers sDd on pt=0)
    // C tile -> LDS
    #pragma unroll
    for (int idx = t; idx < 2048; idx += 256) {
      int pp = idx & 15, h = idx >> 4;
      sCre[pp][h] = Cre[h * NP + p0 + pp];
      sCim[pp][h] = Cim[h * NP + p0 + pp];
    }
    // x tile (regs loaded last iteration) + carry apply -> LDS
    #pragma unroll
    for (int k = 0; k < 8; ++k) {
      int pp = ppb + 2 * k;
      float xr = gx[k].x + gp[k].x * gc[k].x - gp[k].y * gc[k].y;
      float xi = gx[k].y + gp[k].x * gc[k].y + gp[k].y * gc[k].x;
      sXre[pp][lfix] = xr; sXim[pp][lfix] = xi;
    }
    __syncthreads();
    // issue next pt's loads; they complete under the FMA loop below
    if (pt < 3) {
      const int p1 = (pt + 1) * 16;
      #pragma unroll
      for (int k = 0; k < 8; ++k) {
        int pp = ppb + 2 * k;
        gx[k] = xs[((size_t)(b * NP + p1 + pp)) * NL + l0 + lfix];
        gp[k] = powtab[(p1 + pp) * 128 + lfix];
        gc[k] = carryg[((size_t)(b * NCHUNK + c)) * NP + p1 + pp];
      }
    }
    #pragma unroll 4
    for (int pp = 0; pp < 16; ++pp) {
      float4 ca = *(const float4*)&sCre[pp][th * 8];
      float4 cb = *(const float4*)&sCre[pp][th * 8 + 4];
      float4 ia = *(const float4*)&sCim[pp][th * 8];
      float4 ib = *(const float4*)&sCim[pp][th * 8 + 4];
      float4 xa = *(const float4*)&sXre[pp][tl * 8];
      float4 xb = *(const float4*)&sXre[pp][tl * 8 + 4];
      float4 ya = *(const float4*)&sXim[pp][tl * 8];
      float4 yb = *(const float4*)&sXim[pp][tl * 8 + 4];
      float cr[8] = {ca.x, ca.y, ca.z, ca.w, cb.x, cb.y, cb.z, cb.w};
      float ci[8] = {ia.x, ia.y, ia.z, ia.w, ib.x, ib.y, ib.z, ib.w};
      float xr[8] = {xa.x, xa.y, xa.z, xa.w, xb.x, xb.y, xb.z, xb.w};
      float xi[8] = {ya.x, ya.y, ya.z, ya.w, yb.x, yb.y, yb.z, yb.w};
      #pragma unroll
      for (int i = 0; i < 8; ++i)
        #pragma unroll
        for (int j = 0; j < 8; ++j) {
          acc[i][j] = fmaf(cr[i], xr[j], acc[i][j]);
          acc[i][j] = fmaf(-ci[i], xi[j], acc[i][j]);
        }
    }
  }

  #pragma unroll
  for (int i = 0; i < 8; ++i) {
    const int h = th * 8 + i;
    const float dd = sDd[h];
    size_t rb = ((size_t)(b * NH + h)) * NL + l0 + tl * 8;
    float4 u0 = *(const float4*)&u[rb];
    float4 u1 = *(const float4*)&u[rb + 4];
    float uu[8] = {u0.x, u0.y, u0.z, u0.w, u1.x, u1.y, u1.z, u1.w};
    float r[8];
    #pragma unroll
    for (int j = 0; j < 8; ++j) {
      float vv = acc[i][j] + dd * uu[j];
      r[j] = 0.5f * vv * (1.0f + erff(vv * 0.70710678118654752f));
    }
    *(float4*)&out[rb]     = make_float4(r[0], r[1], r[2], r[3]);
    *(float4*)&out[rb + 4] = make_float4(r[4], r[5], r[6], r[7]);
  }
}

extern "C" void kernel_launch(void* const* d_in, const int* in_sizes, int n_in,
                              void* d_out, int out_size, void* d_ws, size_t ws_size,
                              hipStream_t stream) {
  (void)in_sizes; (void)n_in; (void)out_size; (void)ws_size;
  const float* u   = (const float*)d_in[0];
  const float* Lre = (const float*)d_in[1];
  const float* Lim = (const float*)d_in[2];
  const float* Bre = (const float*)d_in[3];
  const float* Bim = (const float*)d_in[4];
  const float* Cre = (const float*)d_in[5];
  const float* Cim = (const float*)d_in[6];
  const float* Dm  = (const float*)d_in[7];
  float* out = (float*)d_out;

  char* wsb = (char*)d_ws;
  float2* xloc   = (float2*)wsb;                              // 64 MiB fp32
  float2* Echunk = (float2*)(wsb + 67108864);                 // 512 KiB
  float2* carryg = (float2*)(wsb + 67108864 + 524288);        // 512 KiB
  float2* powtab = (float2*)(wsb + 67108864 + 1048576);       // 64 KiB

  dim3 g(NL / 128, NB);
  k_bu_scan<<<g, 256, 0, stream>>>(u, Bre, Bim, Lre, Lim, xloc, Echunk);
  dim3 gc(NP, NB);
  k_carry<<<gc, 64, 0, stream>>>(Echunk, Lre, Lim, carryg, powtab);
  k_out<<<g, 256, 0, stream>>>(xloc, u, Cre, Cim, Dm, carryg, powtab, out);
}

// Round 10
// 251.034 us; speedup vs baseline: 1.1663x; 1.0336x over previous
//
#include <hip/hip_runtime.h>
#include <math.h>

#define NB 16
#define NH 128
#define NP 64
#define NL 8192
#define NCHUNK 64   // NL / 128

typedef __attribute__((ext_vector_type(8))) short bf16x8;
typedef __attribute__((ext_vector_type(4))) float f32x4;

__device__ __forceinline__ unsigned toBF(unsigned u) {
  // round-to-nearest-even f32 -> bf16 bits (low 16 of result)
  return (u + 0x7FFFu + ((u >> 16) & 1u)) >> 16;
}

// ---- K1: Bu = B@u fused with chunk-local scan over the 128-l tile ------------
// grid (64, 16), block 256. Writes x_local (chunk-scanned, zero-init, fp32) and
// per-chunk totals Echunk[b][c][p].  (unchanged from R8)
__global__ __launch_bounds__(256) void k_bu_scan(
    const float* __restrict__ u, const float* __restrict__ Bre,
    const float* __restrict__ Bim, const float* __restrict__ Lre,
    const float* __restrict__ Lim, float2* __restrict__ xloc,
    float2* __restrict__ Echunk) {
  __shared__ __align__(16) float sBre[32][68];
  __shared__ float sBim[32][68];
  __shared__ float sU[32][128];
  const int b  = blockIdx.y;
  const int c  = blockIdx.x;
  const int l0 = c * 128;
  const int t  = threadIdx.x;
  const int tp = t & 15;
  const int tl = t >> 4;
  float accRe[4][8], accIm[4][8];
  #pragma unroll
  for (int i = 0; i < 4; ++i)
    #pragma unroll
    for (int j = 0; j < 8; ++j) { accRe[i][j] = 0.f; accIm[i][j] = 0.f; }

  for (int ht = 0; ht < 4; ++ht) {
    const int h0 = ht * 32;
    #pragma unroll
    for (int idx = t; idx < 2048; idx += 256) {
      int h = idx & 31, p = idx >> 5;
      sBre[h][p] = Bre[p * NH + h0 + h];
      sBim[h][p] = Bim[p * NH + h0 + h];
    }
    #pragma unroll
    for (int idx = t; idx < 32 * 128; idx += 256) {
      int l = idx & 127, h = idx >> 7;
      sU[h][l] = u[((size_t)(b * NH + h0 + h)) * NL + l0 + l];
    }
    __syncthreads();
    #pragma unroll 4
    for (int h = 0; h < 32; ++h) {
      float4 br4 = *(const float4*)&sBre[h][tp * 4];
      float4 bi4 = *(const float4*)&sBim[h][tp * 4];
      float4 ua  = *(const float4*)&sU[h][tl * 8];
      float4 ub  = *(const float4*)&sU[h][tl * 8 + 4];
      float uu[8] = {ua.x, ua.y, ua.z, ua.w, ub.x, ub.y, ub.z, ub.w};
      float brr[4] = {br4.x, br4.y, br4.z, br4.w};
      float bii[4] = {bi4.x, bi4.y, bi4.z, bi4.w};
      #pragma unroll
      for (int i = 0; i < 4; ++i)
        #pragma unroll
        for (int j = 0; j < 8; ++j) {
          accRe[i][j] = fmaf(brr[i], uu[j], accRe[i][j]);
          accIm[i][j] = fmaf(bii[i], uu[j], accIm[i][j]);
        }
    }
    __syncthreads();
  }

  float lr[4], li[4];
  #pragma unroll
  for (int i = 0; i < 4; ++i) { lr[i] = Lre[tp * 4 + i]; li[i] = Lim[tp * 4 + i]; }
  #pragma unroll
  for (int i = 0; i < 4; ++i) {
    float xr = 0.f, xi = 0.f;
    #pragma unroll
    for (int j = 0; j < 8; ++j) {
      float nr = fmaf(lr[i], xr, fmaf(-li[i], xi, accRe[i][j]));
      float ni = fmaf(lr[i], xi, fmaf( li[i], xr, accIm[i][j]));
      xr = nr; xi = ni; accRe[i][j] = xr; accIm[i][j] = xi;
    }
  }

  float2* E = reinterpret_cast<float2*>(&sBre[0][0]);
  #define EL(p, q) E[(p) * 17 + (q)]
  #pragma unroll
  for (int i = 0; i < 4; ++i)
    EL(tp * 4 + i, tl) = make_float2(accRe[i][7], accIm[i][7]);

  float wr[4], wi[4];
  #pragma unroll
  for (int i = 0; i < 4; ++i) {
    float ar = lr[i], ai = li[i];
    #pragma unroll
    for (int k = 0; k < 3; ++k) { float nr = ar * ar - ai * ai; ai = 2.f * ar * ai; ar = nr; }
    wr[i] = ar; wi[i] = ai;
  }
  __syncthreads();
  #pragma unroll
  for (int d = 1; d < 16; d <<= 1) {
    float2 rv[4];
    #pragma unroll
    for (int i = 0; i < 4; ++i)
      rv[i] = (tl >= d) ? EL(tp * 4 + i, tl - d) : make_float2(0.f, 0.f);
    __syncthreads();
    if (tl >= d) {
      #pragma unroll
      for (int i = 0; i < 4; ++i) {
        float2 cur = EL(tp * 4 + i, tl);
        cur.x += wr[i] * rv[i].x - wi[i] * rv[i].y;
        cur.y += wr[i] * rv[i].y + wi[i] * rv[i].x;
        EL(tp * 4 + i, tl) = cur;
      }
    }
    __syncthreads();
    #pragma unroll
    for (int i = 0; i < 4; ++i) {
      float nr = wr[i] * wr[i] - wi[i] * wi[i];
      wi[i] = 2.f * wr[i] * wi[i]; wr[i] = nr;
    }
  }

  float2 cin[4];
  #pragma unroll
  for (int i = 0; i < 4; ++i)
    cin[i] = (tl > 0) ? EL(tp * 4 + i, tl - 1) : make_float2(0.f, 0.f);
  if (t < 64) {
    float2 tot = EL(t, 15);
    Echunk[((size_t)(b * NCHUNK + c)) * NP + t] = tot;
  }

  #pragma unroll
  for (int i = 0; i < 4; ++i) {
    float cr = cin[i].x, ci = cin[i].y;
    #pragma unroll
    for (int j = 0; j < 8; ++j) {
      float nr = lr[i] * cr - li[i] * ci;
      float nc = lr[i] * ci + li[i] * cr;
      cr = nr; ci = nc;
      accRe[i][j] += cr; accIm[i][j] += ci;
    }
  }

  #pragma unroll
  for (int i = 0; i < 4; ++i) {
    size_t base = ((size_t)(b * NP + tp * 4 + i)) * NL + l0 + tl * 8;
    #pragma unroll
    for (int j = 0; j < 8; j += 2) {
      float4 v = make_float4(accRe[i][j], accIm[i][j], accRe[i][j + 1], accIm[i][j + 1]);
      *(float4*)&xloc[base + j] = v;
    }
  }
  #undef EL
}

// ---- K2: parallel carry scan (unchanged from R8) -----------------------------
__global__ __launch_bounds__(64) void k_carry(
    const float2* __restrict__ Echunk, const float* __restrict__ Lre,
    const float* __restrict__ Lim, float2* __restrict__ carryg,
    float2* __restrict__ powtab) {
  const int p = blockIdx.x;
  const int b = blockIdx.y;
  const int t = threadIdx.x;
  const float lr = Lre[p], li = Lim[p];
  float wr = lr, wi = li;
  #pragma unroll
  for (int k = 0; k < 7; ++k) { float nr = wr * wr - wi * wi; wi = 2.f * wr * wi; wr = nr; }
  float2 e = Echunk[((size_t)(b * NCHUNK + t)) * NP + p];
  float sr = e.x, si = e.y;
  float fr = wr, fi = wi;
  #pragma unroll
  for (int d = 1; d < 64; d <<= 1) {
    float pr = __shfl_up(sr, d);
    float pi = __shfl_up(si, d);
    if (t >= d) { sr += fr * pr - fi * pi; si += fr * pi + fi * pr; }
    float nr = fr * fr - fi * fi; fi = 2.f * fr * fi; fr = nr;
  }
  float cr = __shfl_up(sr, 1);
  float ci = __shfl_up(si, 1);
  if (t == 0) { cr = 0.f; ci = 0.f; }
  carryg[((size_t)(b * NCHUNK + t)) * NP + p] = make_float2(cr, ci);

  if (b == 0) {
    float ar = lr, ai = li, br = 1.f, bi = 0.f;
    int e1 = t + 1;
    while (e1) {
      if (e1 & 1) { float nr = br * ar - bi * ai; bi = br * ai + bi * ar; br = nr; }
      float nr = ar * ar - ai * ai; ai = 2.f * ar * ai; ar = nr;
      e1 >>= 1;
    }
    powtab[p * 128 + t] = make_float2(br, bi);
    float qr = lr, qi = li;
    #pragma unroll
    for (int k = 0; k < 6; ++k) { float nr = qr * qr - qi * qi; qi = 2.f * qr * qi; qr = nr; }
    float hr = br * qr - bi * qi, hi = br * qi + bi * qr;
    powtab[p * 128 + t + 64] = make_float2(hr, hi);
  }
}

// ---- K3: MFMA version. out = gelu( Re(C@x) + diag(D)*u ) ---------------------
// Real GEMM: A=[Cre | -Cim] (128h x 128k bf16), B=[xre ; xim] (128k x 64l bf16),
// K folded over {re,im}x{p}. grid (NL/64=128, NB), block 256 = 4 waves.
// Wave w owns l-cols [w*16, w*16+16); 8 M-tiles x K-loop(4) = 32 MFMA/wave.
__global__ __launch_bounds__(256) void k_out_mfma(
    const float2* __restrict__ xs, const float* __restrict__ u,
    const float* __restrict__ Cre, const float* __restrict__ Cim,
    const float* __restrict__ D, const float2* __restrict__ carryg,
    const float2* __restrict__ powtab, float* __restrict__ out) {
  __shared__ __align__(16) unsigned short Asl[128][136];  // 34816 B, row 272B (16B-aligned)
  __shared__ __align__(16) unsigned short Bsl[64][136];   // 17408 B
  __shared__ float sDd[128];
  const int b  = blockIdx.y;
  const int l0 = blockIdx.x * 64;
  const int t  = threadIdx.x;
  const int lane = t & 63, w = t >> 6;

  if (t < 128) sDd[t] = D[t * NH + t];

  // Stage A = [Cre | -Cim] as bf16: rows h, cols p / 64+p
  for (int idx = t; idx < NH * NP; idx += 256) {
    int h = idx >> 6, p = idx & 63;
    Asl[h][p]      = (unsigned short)toBF(__float_as_uint(Cre[h * NP + p]));
    Asl[h][64 + p] = (unsigned short)toBF(__float_as_uint(-Cim[h * NP + p]));
  }

  // Stage B = [xre ; xim] with carry applied: rows n=l(local), cols p / 64+p
  {
    const int l  = t & 63, pb = t >> 6;
    const int c  = l0 >> 7;                 // scan chunk (128-wide) this block is in
    const int jj = (l0 & 127) + l;          // position within the chunk
    #pragma unroll
    for (int i = 0; i < 16; ++i) {
      int p = pb * 16 + i;
      float2 gx = xs[((size_t)(b * NP + p)) * NL + l0 + l];
      float2 gp = powtab[p * 128 + jj];
      float2 gc = carryg[((size_t)(b * NCHUNK + c)) * NP + p];
      float xr = gx.x + gp.x * gc.x - gp.y * gc.y;
      float xi = gx.y + gp.x * gc.y + gp.y * gc.x;
      Bsl[l][p]      = (unsigned short)toBF(__float_as_uint(xr));
      Bsl[l][64 + p] = (unsigned short)toBF(__float_as_uint(xi));
    }
  }
  __syncthreads();

  const int r16 = lane & 15, kq = lane >> 4;   // frag row/col idx, k-quarter
  f32x4 acc[8];
  #pragma unroll
  for (int mt = 0; mt < 8; ++mt) acc[mt] = (f32x4){0.f, 0.f, 0.f, 0.f};

  bf16x8 bfr[4];
  #pragma unroll
  for (int kt = 0; kt < 4; ++kt)
    bfr[kt] = *(const bf16x8*)&Bsl[w * 16 + r16][kt * 32 + kq * 8];

  #pragma unroll
  for (int mt = 0; mt < 8; ++mt) {
    #pragma unroll
    for (int kt = 0; kt < 4; ++kt) {
      bf16x8 a = *(const bf16x8*)&Asl[mt * 16 + r16][kt * 32 + kq * 8];
      acc[mt] = __builtin_amdgcn_mfma_f32_16x16x32_bf16(a, bfr[kt], acc[mt], 0, 0, 0);
    }
  }

  // epilogue: D frag layout col=lane&15 (=l), row=(lane>>4)*4+reg (=h within tile)
  const int lcol = l0 + w * 16 + r16;
  #pragma unroll
  for (int mt = 0; mt < 8; ++mt) {
    #pragma unroll
    for (int r = 0; r < 4; ++r) {
      int h = mt * 16 + kq * 4 + r;
      size_t o = ((size_t)(b * NH + h)) * NL + lcol;
      float vv = acc[mt][r] + sDd[h] * u[o];
      out[o] = 0.5f * vv * (1.0f + erff(vv * 0.70710678118654752f));
    }
  }
}

extern "C" void kernel_launch(void* const* d_in, const int* in_sizes, int n_in,
                              void* d_out, int out_size, void* d_ws, size_t ws_size,
                              hipStream_t stream) {
  (void)in_sizes; (void)n_in; (void)out_size; (void)ws_size;
  const float* u   = (const float*)d_in[0];
  const float* Lre = (const float*)d_in[1];
  const float* Lim = (const float*)d_in[2];
  const float* Bre = (const float*)d_in[3];
  const float* Bim = (const float*)d_in[4];
  const float* Cre = (const float*)d_in[5];
  const float* Cim = (const float*)d_in[6];
  const float* Dm  = (const float*)d_in[7];
  float* out = (float*)d_out;

  char* wsb = (char*)d_ws;
  float2* xloc   = (float2*)wsb;                              // 64 MiB fp32
  float2* Echunk = (float2*)(wsb + 67108864);                 // 512 KiB
  float2* carryg = (float2*)(wsb + 67108864 + 524288);        // 512 KiB
  float2* powtab = (float2*)(wsb + 67108864 + 1048576);       // 64 KiB

  dim3 g1(NL / 128, NB);
  k_bu_scan<<<g1, 256, 0, stream>>>(u, Bre, Bim, Lre, Lim, xloc, Echunk);
  dim3 gc(NP, NB);
  k_carry<<<gc, 64, 0, stream>>>(Echunk, Lre, Lim, carryg, powtab);
  dim3 g3(NL / 64, NB);
  k_out_mfma<<<g3, 256, 0, stream>>>(xloc, u, Cre, Cim, Dm, carryg, powtab, out);
}